// Round 3
// baseline (86.218 us; speedup 1.0000x reference)
//
#include <hip/hip_runtime.h>
#include <cstdint>

// MHSA: B=2, N=2048, D_IN=1024, D_MODEL=1024, H=16, DEPTH=64
// cvt (merged) -> fused QKV GEMM (dbuf LDS, XOR-swizzled, COUNTED vmcnt
// two-barrier pipeline, LDS-staged coalesced Q/K epilogue) -> flash attn
// (R15 config + counted vmcnt two-barrier pipeline).

#define SEQ_N 2048
#define NHEAD 16
#define DEPTH 64
#define SCALE_Q (0.125f * 1.44269504088896340736f)   // 1/sqrt(64) * log2(e); softmax uses exp2
#define M_OFF (-12.0f)   // fixed softmax offset in log2 units; S~N(0,1.44^2), |S|max ~ 9 << 12

typedef short bf16x8 __attribute__((ext_vector_type(8)));
typedef short short4v __attribute__((ext_vector_type(4)));
typedef float f32x4 __attribute__((ext_vector_type(4)));

#define MFMA32(a, b, c) __builtin_amdgcn_mfma_f32_16x16x32_bf16((a), (b), (c), 0, 0, 0)

#if defined(__has_builtin)
#if __has_builtin(__builtin_amdgcn_exp2f)
#define FEXP2(x) __builtin_amdgcn_exp2f(x)
#endif
#endif
#ifndef FEXP2
#define FEXP2(x) exp2f(x)
#endif

__device__ __forceinline__ short f2b(float f) {
    union { float f; unsigned u; } v; v.f = f;
    unsigned u = v.u;
    return (short)((u + 0x7FFFu + ((u >> 16) & 1u)) >> 16);   // RNE f32->bf16
}

__device__ __forceinline__ unsigned cvt_pk_bf16(float lo, float hi) {
    unsigned r;
    asm("v_cvt_pk_bf16_f32 %0, %1, %2" : "=v"(r) : "v"(lo), "v"(hi));
    return r;
}

__device__ __forceinline__ void gld_lds16(const void* g, void* l) {
    __builtin_amdgcn_global_load_lds(
        (const __attribute__((address_space(1))) unsigned int*)(uintptr_t)g,
        (__attribute__((address_space(3))) unsigned int*)(uintptr_t)l, 16, 0, 0);
}

// ---------------- merged conversions: x -> bf16 (blocks 0..2047),
// ---------------- W -> WT bf16 transpose (blocks 2048..2815) ----------------
__global__ __launch_bounds__(256) void cvt_all_kernel(
    const float* __restrict__ x, short* __restrict__ xb,
    const float* __restrict__ Wq, const float* __restrict__ Wk,
    const float* __restrict__ Wv, short* __restrict__ WT)
{
    __shared__ float tile[64][65];
    if (blockIdx.x < 2048) {
        const int i = blockIdx.x * 256 + threadIdx.x;
        const float4* xi = (const float4*)x + (size_t)i * 2;
        const float4 a = xi[0], c = xi[1];
        bf16x8 o;
        o[0] = f2b(a.x); o[1] = f2b(a.y); o[2] = f2b(a.z); o[3] = f2b(a.w);
        o[4] = f2b(c.x); o[5] = f2b(c.y); o[6] = f2b(c.z); o[7] = f2b(c.w);
        *((bf16x8*)xb + i) = o;
        return;
    }
    const int bid = blockIdx.x - 2048;
    const int mat = bid >> 8;
    const int t = bid & 255;
    const int k0 = (t >> 4) * 64, n0 = (t & 15) * 64;
    const float* W = (mat == 0) ? Wq : ((mat == 1) ? Wk : Wv);
    const int tt = threadIdx.x;
#pragma unroll
    for (int i = 0; i < 16; ++i) {
        const int idx = tt + i * 256;
        const int r = idx >> 6, c = idx & 63;
        tile[r][c] = W[(size_t)(k0 + r) * 1024 + n0 + c];
    }
    __syncthreads();
#pragma unroll
    for (int i = 0; i < 16; ++i) {
        const int idx = tt + i * 256;
        const int r = idx >> 6, c = idx & 63;
        WT[(size_t)(mat * 1024 + n0 + r) * 1024 + k0 + c] = f2b(tile[c][r]);
    }
}

// ---------------- fused QKV GEMM: Q/K -> [bh][N][64], V -> VT_perm [bh][64][N'] ----------------
// Counted-vmcnt two-barrier pipeline: stage(t+1); vmcnt(4) waits only the
// oldest 4 loads (tile t); barrier; ds_read+MFMA; barrier (WAR guard).
// Loads for tile t+1 stay in flight across both barriers.
// Q/K epilogue staged through LDS ([128][136] bf16) for contiguous dwordx4 stores.
#define GEMM_K 1024
#define GEMM_NK (GEMM_K / 32)

__global__ __launch_bounds__(256) void qkv_gemm_kernel(
    const short* __restrict__ A, const short* __restrict__ BT,
    const float* __restrict__ bq, const float* __restrict__ bk, const float* __restrict__ bv,
    short* __restrict__ Qb, short* __restrict__ Kb, short* __restrict__ VTb)
{
    // 34816 B: loop uses [0..16383] as As[2]/Bs[2]; epilogue reuses as [128][136]
    __shared__ __align__(16) short sm[17408];
    const int tid = threadIdx.x;
    const int l = tid & 63;
    const int w = tid >> 6;
    const int wr = w >> 1, wc = w & 1;
    const int bm = blockIdx.x & 31;
    const int bn = blockIdx.x >> 5;
    const int row0 = bm * 128, col0 = bn * 128;
    const int lr = l & 15, lk = l >> 4;

    const int r0 = tid >> 2;
    const int g0 = (tid & 3) ^ ((r0 >> 1) & 3);
    const int g1 = (tid & 3) ^ (((r0 + 64) >> 1) & 3);
    const int sw = (lr >> 1) & 3;
    const int aA = (wr * 64 + lr) * 32 + ((lk ^ sw) << 3);
    const int aB = (wc * 64 + lr) * 32 + ((lk ^ sw) << 3);

    // base src pointers (per-thread), advance by kt*32 elements per iter
    const short* As0 = A + (size_t)(row0 + r0) * GEMM_K + g0 * 8;
    const short* As1 = A + (size_t)(row0 + r0 + 64) * GEMM_K + g1 * 8;
    const short* Bs0 = BT + (size_t)(col0 + r0) * GEMM_K + g0 * 8;
    const short* Bs1 = BT + (size_t)(col0 + r0 + 64) * GEMM_K + g1 * 8;

#define GSTAGE(BUF, KT)                                            \
    do {                                                           \
        short* asb = sm + (BUF) * 4096;                            \
        short* bsb = sm + 8192 + (BUF) * 4096;                     \
        gld_lds16(As0 + (KT) * 32, &asb[tid * 8]);                 \
        gld_lds16(Bs0 + (KT) * 32, &bsb[tid * 8]);                 \
        gld_lds16(As1 + (KT) * 32, &asb[2048 + tid * 8]);          \
        gld_lds16(Bs1 + (KT) * 32, &bsb[2048 + tid * 8]);          \
    } while (0)

    f32x4 acc[4][4];
#pragma unroll
    for (int m = 0; m < 4; ++m)
#pragma unroll
        for (int n = 0; n < 4; ++n) acc[m][n] = (f32x4){0.f, 0.f, 0.f, 0.f};

    GSTAGE(0, 0);

#pragma unroll 2
    for (int kt = 0; kt < GEMM_NK; ++kt) {
        const int cur = kt & 1;
        if (kt + 1 < GEMM_NK) {
            GSTAGE(cur ^ 1, kt + 1);
            asm volatile("s_waitcnt vmcnt(4)" ::: "memory");   // oldest 4 = tile kt
        } else {
            asm volatile("s_waitcnt vmcnt(0)" ::: "memory");
        }
        __builtin_amdgcn_s_barrier();
        __builtin_amdgcn_sched_barrier(0);

        const short* asb = sm + cur * 4096;
        const short* bsb = sm + 8192 + cur * 4096;
        bf16x8 af[4], bfr[4];
#pragma unroll
        for (int m = 0; m < 4; ++m)
            af[m] = *(const bf16x8*)(asb + m * 512 + aA);
#pragma unroll
        for (int n = 0; n < 4; ++n)
            bfr[n] = *(const bf16x8*)(bsb + n * 512 + aB);
#pragma unroll
        for (int m = 0; m < 4; ++m)
#pragma unroll
            for (int n = 0; n < 4; ++n)
                acc[m][n] = MFMA32(af[m], bfr[n], acc[m][n]);

        __builtin_amdgcn_sched_barrier(0);
        __builtin_amdgcn_s_barrier();      // WAR: next iter overwrites buf[cur^1... -> buf[cur]]
    }
#undef GSTAGE

    const int matb = bn >> 3;   // block-uniform: 0=Q, 1=K, 2=V
    if (matb < 2) {
        // ---- LDS-staged coalesced epilogue for Q/K ----
        short* Ct = sm;   // [128][136] bf16 (row stride 272 B = 16B-aligned)
        short* O = (matb == 0) ? Qb : Kb;
        const float sc = (matb == 0) ? SCALE_Q : 1.0f;
        const float* bias = (matb == 0) ? bq : bk;
#pragma unroll
        for (int n = 0; n < 4; ++n) {
            const int lc = wc * 64 + n * 16 + lr;
            const float bb_ = bias[(col0 + lc) & 1023];
#pragma unroll
            for (int m = 0; m < 4; ++m) {
                const int lrow = wr * 64 + m * 16 + lk * 4;
#pragma unroll
                for (int r = 0; r < 4; ++r)
                    Ct[(lrow + r) * 136 + lc] = f2b((acc[m][n][r] + bb_) * sc);
            }
        }
        __builtin_amdgcn_s_barrier();
        const int row = tid >> 1, seg = tid & 1;
        const int h = ((col0 + seg * 64) & 1023) >> 6;
        const int grow = row0 + row;
        const int bb2 = grow >> 11, ns = grow & 2047;
        const int4* src = (const int4*)(Ct + row * 136 + seg * 64);
        int4* dst = (int4*)(O + (size_t)((bb2 * NHEAD + h) * SEQ_N + ns) * DEPTH);
#pragma unroll
        for (int i = 0; i < 8; ++i) dst[i] = src[i];
    } else {
        // ---- V^T with per-64-block column permutation (8B stores) ----
#pragma unroll
        for (int n = 0; n < 4; ++n) {
            const int jj = (col0 + wc * 64 + n * 16 + lr) & 1023;
            const float bias = bv[jj];
            const int h = jj >> 6, d = jj & 63;
#pragma unroll
            for (int m = 0; m < 4; ++m) {
                const int grow0 = row0 + wr * 64 + m * 16 + lk * 4;
                const int bb = grow0 >> 11, ns0 = grow0 & 2047;
                const int g = (ns0 >> 2) & 15;
                const int gp = (g & 8) | ((g & 3) << 1) | ((g >> 2) & 1);
                const int nsp = (ns0 & ~63) | (gp << 2);
                short4v pv;
#pragma unroll
                for (int r = 0; r < 4; ++r) pv[r] = f2b(acc[m][n][r] + bias);
                *(short4v*)(VTb + ((size_t)(bb * NHEAD + h) * DEPTH + d) * SEQ_N + nsp) = pv;
            }
        }
    }
}

// ---------------- flash attention (R16: counted-vmcnt two-barrier pipeline) ----
// 4 waves x 32 q = 128 q rows per block; grid = 32 bh x 16 q-tiles = 512 blocks
// -> 2 blocks/CU (64 KB LDS each). Super-tile = 128 keys (2 x 64 sub-tiles),
// double-buffered LDS. Per super-tile: stage(t+1); vmcnt(8) waits only the
// oldest 8 loads (tile t); barrier; compute; barrier (WAR).
// Fixed-offset softmax: S accumulator initialized to M_OFF=-12; P = exp2(S)
// directly (no running max / no rescale; exact softmax ratios, bf16-safe).
// l: per-lane VALU partials reduced via shfl_xor(16/32) in the epilogue.

__device__ __forceinline__ float exppack32_lane(const f32x4 s[4], bf16x8 pb[2]) {
    float rs = 0.f;
#pragma unroll
    for (int kk = 0; kk < 2; ++kk) {
        union { unsigned u[4]; bf16x8 v; } pk;
#pragma unroll
        for (int hh = 0; hh < 2; ++hh) {
            const int c = 2 * kk + hh;
            const float p0 = FEXP2(s[c][0]);
            const float p1 = FEXP2(s[c][1]);
            const float p2 = FEXP2(s[c][2]);
            const float p3 = FEXP2(s[c][3]);
            rs += (p0 + p1) + (p2 + p3);
            pk.u[2 * hh]     = cvt_pk_bf16(p0, p1);
            pk.u[2 * hh + 1] = cvt_pk_bf16(p2, p3);
        }
        pb[kk] = pk.v;
    }
    return rs;   // per-lane partial; reduced across lk at the very end
}

#define NT 16   // 2048 / 128 super-tiles

__global__ __launch_bounds__(256, 2) void attn_kernel(
    const short* __restrict__ Qb, const short* __restrict__ Kb,
    const short* __restrict__ VTb, float* __restrict__ out)
{
    __shared__ short smem[2][16384];   // [buf][K0|K1|V0|V1] = 64 KB

    const int tid = threadIdx.x;
    const int l = tid & 63, w = tid >> 6;     // 4 waves
    const int lr = l & 15, lk = l >> 4;

    // XCD swizzle: 512 blocks -> 64/XCD = 4 bh x 16 q-tiles contiguous per XCD
    const int hb = blockIdx.x;
    const int slot = hb >> 3;                 // 0..63
    const int bh = (hb & 7) * 4 + (slot >> 4);
    const int qt = slot & 15;
    const int b = bh >> 4, h = bh & 15;

    const int qw = qt * 128 + w * 32;   // wave owns 32 q rows (2 groups of 16)

    const short* Qg = Qb + ((size_t)bh * SEQ_N + qw + lr) * DEPTH + lk * 8;
    const bf16x8 bq00 = *(const bf16x8*)(Qg);
    const bf16x8 bq01 = *(const bf16x8*)(Qg + 32);
    const bf16x8 bq10 = *(const bf16x8*)(Qg + 16 * DEPTH);
    const bf16x8 bq11 = *(const bf16x8*)(Qg + 16 * DEPTH + 32);

    const short* Kg = Kb + (size_t)bh * SEQ_N * DEPTH;    // [key][d]
    const short* Vg = VTb + (size_t)bh * DEPTH * SEQ_N;   // [d][key'] (permuted)

    // staging (256 thr): thread covers 16B chunk tid per 4KB half-region;
    // LDS[row][gl] = global[row][gl^(row&7)]; (row+32)&7 == row&7 so same granule.
    const int srow = tid >> 3;                // 0..31
    const int sg = (tid & 7) ^ (srow & 7);
    const short* Ksrc = Kg + (size_t)srow * DEPTH + sg * 8;   // + key*DEPTH per call
    const short* Vsrc = Vg + (size_t)srow * SEQ_N + sg * 8;   // + key per call

#define STAGE(BUF, T)                                                            \
    do {                                                                         \
        const int key0_ = (T) * 128;                                             \
        short* dst = &smem[BUF][w * 512];                                        \
        gld_lds16(Ksrc + (size_t)key0_ * DEPTH, dst);                            \
        gld_lds16(Ksrc + (size_t)(key0_ + 32) * DEPTH, dst + 2048);              \
        gld_lds16(Ksrc + (size_t)(key0_ + 64) * DEPTH, dst + 4096);              \
        gld_lds16(Ksrc + (size_t)(key0_ + 96) * DEPTH, dst + 6144);              \
        gld_lds16(Vsrc + key0_, dst + 8192);                                     \
        gld_lds16(Vsrc + key0_ + 32 * SEQ_N, dst + 10240);                       \
        gld_lds16(Vsrc + key0_ + 64, dst + 12288);                               \
        gld_lds16(Vsrc + key0_ + 64 + 32 * SEQ_N, dst + 14336);                  \
    } while (0)

    // hoisted per-lane fragment offsets (elements): row base + XOR granule
    const short* s0p = &smem[0][0];
    const int aoff0 = lr * 64 + (((lk    ) ^ (lr & 7)) << 3);   // kk=0
    const int aoff1 = lr * 64 + (((lk + 4) ^ (lr & 7)) << 3);   // kk=1

    f32x4 acc0[4], acc1[4];
#pragma unroll
    for (int n = 0; n < 4; ++n) {
        acc0[n] = (f32x4){0.f, 0.f, 0.f, 0.f};
        acc1[n] = (f32x4){0.f, 0.f, 0.f, 0.f};
    }
    float l0 = 0.f, l1 = 0.f;

    // prologue: stage super-tile 0 (waited by iter 0's counted vmcnt)
    STAGE(0, 0);

#pragma unroll 2
    for (int t = 0; t < NT; ++t) {
        const int cur = t & 1;
        if (t + 1 < NT) {
            STAGE(cur ^ 1, t + 1);
            asm volatile("s_waitcnt vmcnt(8)" ::: "memory");   // oldest 8 = tile t
        } else {
            asm volatile("s_waitcnt vmcnt(0)" ::: "memory");
        }
        __builtin_amdgcn_s_barrier();
        __builtin_amdgcn_sched_barrier(0);

        // two 64-key sub-tiles, wave-staggered order, no barrier between them
#pragma unroll
        for (int ss = 0; ss < 2; ++ss) {
            const int sub = ss ^ (w & 1);
            const short* Kl = s0p + cur * 16384 + sub * 4096;
            const short* Vl = Kl + 8192;

            bf16x8 kf[4][2], vf[4][2];
#pragma unroll
            for (int c = 0; c < 4; ++c) {
                kf[c][0] = *(const bf16x8*)(Kl + c * 1024 + aoff0);
                kf[c][1] = *(const bf16x8*)(Kl + c * 1024 + aoff1);
            }
#pragma unroll
            for (int n = 0; n < 4; ++n) {
                vf[n][0] = *(const bf16x8*)(Vl + n * 1024 + aoff0);
                vf[n][1] = *(const bf16x8*)(Vl + n * 1024 + aoff1);
            }

            // QK^T with C init = M_OFF (bakes the fixed softmax offset)
            f32x4 s0[4], s1[4];
            __builtin_amdgcn_s_setprio(1);
#pragma unroll
            for (int c = 0; c < 4; ++c) {
                f32x4 a = (f32x4){M_OFF, M_OFF, M_OFF, M_OFF};
                a = MFMA32(kf[c][0], bq00, a);
                a = MFMA32(kf[c][1], bq01, a);
                s0[c] = a;
                f32x4 bb2 = (f32x4){M_OFF, M_OFF, M_OFF, M_OFF};
                bb2 = MFMA32(kf[c][0], bq10, bb2);
                bb2 = MFMA32(kf[c][1], bq11, bb2);
                s1[c] = bb2;
            }
            __builtin_amdgcn_s_setprio(0);

            // fixed-offset softmax: P = exp2(s) directly, pack to bf16
            bf16x8 pb0[2], pb1[2];
            l0 += exppack32_lane(s0, pb0);
            l1 += exppack32_lane(s1, pb1);

            // PV over permuted key order
            __builtin_amdgcn_s_setprio(1);
#pragma unroll
            for (int n = 0; n < 4; ++n) {
                acc0[n] = MFMA32(vf[n][0], pb0[0], acc0[n]);
                acc0[n] = MFMA32(vf[n][1], pb0[1], acc0[n]);
                acc1[n] = MFMA32(vf[n][0], pb1[0], acc1[n]);
                acc1[n] = MFMA32(vf[n][1], pb1[1], acc1[n]);
            }
            __builtin_amdgcn_s_setprio(0);
        }

        __builtin_amdgcn_sched_barrier(0);
        __builtin_amdgcn_s_barrier();   // WAR: next iter's stage overwrites buf[cur]
    }
#undef STAGE

    // final cross-lane l reduction (row-mates lk=0..3 hold disjoint key subsets)
    l0 += __shfl_xor(l0, 16); l0 += __shfl_xor(l0, 32);
    l1 += __shfl_xor(l1, 16); l1 += __shfl_xor(l1, 32);

    const float inv0 = 1.0f / l0, inv1 = 1.0f / l1;
    float* o0 = out + ((size_t)b * SEQ_N + qw + lr) * 1024 + h * 64 + lk * 4;
    float* o1 = o0 + (size_t)16 * 1024;
#pragma unroll
    for (int n = 0; n < 4; ++n) {
        const f32x4 v0 = acc0[n] * inv0;
        const f32x4 v1 = acc1[n] * inv1;
        *(f32x4*)(o0 + n * 16) = v0;
        *(f32x4*)(o1 + n * 16) = v1;
    }
}

extern "C" void kernel_launch(void* const* d_in, const int* in_sizes, int n_in,
                              void* d_out, int out_size, void* d_ws, size_t ws_size,
                              hipStream_t stream) {
    const float* x  = (const float*)d_in[0];
    const float* Wq = (const float*)d_in[1];
    const float* bq = (const float*)d_in[2];
    const float* Wk = (const float*)d_in[3];
    const float* bk = (const float*)d_in[4];
    const float* Wv = (const float*)d_in[5];
    const float* bv = (const float*)d_in[6];
    float* out = (float*)d_out;

    char* ws = (char*)d_ws;
    short* xb  = (short*)(ws);                      // 8 MB
    short* WT  = (short*)(ws + (8  << 20));         // 6 MB
    short* Qb  = (short*)(ws + (14 << 20));         // 8 MB
    short* Kb  = (short*)(ws + (22 << 20));         // 8 MB
    short* VTb = (short*)(ws + (30 << 20));         // 8 MB

    cvt_all_kernel<<<2816, 256, 0, stream>>>(x, xb, Wq, Wk, Wv, WT);
    qkv_gemm_kernel<<<32 * 24, 256, 0, stream>>>(xb, WT, bq, bk, bv, Qb, Kb, VTb);
    attn_kernel<<<512, 256, 0, stream>>>(Qb, Kb, VTb, out);
}

// Round 5
// 82.491 us; speedup vs baseline: 1.0452x; 1.0452x over previous
//
#include <hip/hip_runtime.h>
#include <cstdint>

// MHSA: B=2, N=2048, D_IN=1024, D_MODEL=1024, H=16, DEPTH=64
// cvt (merged) -> fused QKV GEMM v2 (256x192 tile, BK=64, 8 waves, 4-phase
// deep pipeline w/ counted vmcnt + setprio, XOR-swizzled LDS, grid 256 = 1
// block/CU) -> flash attn (R15 config: 4 waves, 2 blocks/CU, fixed-offset
// softmax).  R18 = R17 + fixed Q/K writeout (12 granules/thread, was 6 —
// half the columns were never stored).

#define SEQ_N 2048
#define NHEAD 16
#define DEPTH 64
#define SCALE_Q (0.125f * 1.44269504088896340736f)   // 1/sqrt(64) * log2(e); softmax uses exp2
#define M_OFF (-12.0f)   // fixed softmax offset in log2 units; S~N(0,1.44^2), |S|max ~ 9 << 12

typedef short bf16x8 __attribute__((ext_vector_type(8)));
typedef short short4v __attribute__((ext_vector_type(4)));
typedef float f32x4 __attribute__((ext_vector_type(4)));

#define MFMA32(a, b, c) __builtin_amdgcn_mfma_f32_16x16x32_bf16((a), (b), (c), 0, 0, 0)

#if defined(__has_builtin)
#if __has_builtin(__builtin_amdgcn_exp2f)
#define FEXP2(x) __builtin_amdgcn_exp2f(x)
#endif
#endif
#ifndef FEXP2
#define FEXP2(x) exp2f(x)
#endif

__device__ __forceinline__ short f2b(float f) {
    union { float f; unsigned u; } v; v.f = f;
    unsigned u = v.u;
    return (short)((u + 0x7FFFu + ((u >> 16) & 1u)) >> 16);   // RNE f32->bf16
}

__device__ __forceinline__ unsigned cvt_pk_bf16(float lo, float hi) {
    unsigned r;
    asm("v_cvt_pk_bf16_f32 %0, %1, %2" : "=v"(r) : "v"(lo), "v"(hi));
    return r;
}

__device__ __forceinline__ void gld_lds16(const void* g, void* l) {
    __builtin_amdgcn_global_load_lds(
        (const __attribute__((address_space(1))) unsigned int*)(uintptr_t)g,
        (__attribute__((address_space(3))) unsigned int*)(uintptr_t)l, 16, 0, 0);
}

// ---------------- merged conversions: x -> bf16 (blocks 0..2047),
// ---------------- W -> WT bf16 transpose (blocks 2048..2815) ----------------
__global__ __launch_bounds__(256) void cvt_all_kernel(
    const float* __restrict__ x, short* __restrict__ xb,
    const float* __restrict__ Wq, const float* __restrict__ Wk,
    const float* __restrict__ Wv, short* __restrict__ WT)
{
    __shared__ float tile[64][65];
    if (blockIdx.x < 2048) {
        const int i = blockIdx.x * 256 + threadIdx.x;
        const float4* xi = (const float4*)x + (size_t)i * 2;
        const float4 a = xi[0], c = xi[1];
        bf16x8 o;
        o[0] = f2b(a.x); o[1] = f2b(a.y); o[2] = f2b(a.z); o[3] = f2b(a.w);
        o[4] = f2b(c.x); o[5] = f2b(c.y); o[6] = f2b(c.z); o[7] = f2b(c.w);
        *((bf16x8*)xb + i) = o;
        return;
    }
    const int bid = blockIdx.x - 2048;
    const int mat = bid >> 8;
    const int t = bid & 255;
    const int k0 = (t >> 4) * 64, n0 = (t & 15) * 64;
    const float* W = (mat == 0) ? Wq : ((mat == 1) ? Wk : Wv);
    const int tt = threadIdx.x;
#pragma unroll
    for (int i = 0; i < 16; ++i) {
        const int idx = tt + i * 256;
        const int r = idx >> 6, c = idx & 63;
        tile[r][c] = W[(size_t)(k0 + r) * 1024 + n0 + c];
    }
    __syncthreads();
#pragma unroll
    for (int i = 0; i < 16; ++i) {
        const int idx = tt + i * 256;
        const int r = idx >> 6, c = idx & 63;
        WT[(size_t)(mat * 1024 + n0 + r) * 1024 + k0 + c] = f2b(tile[c][r]);
    }
}

// ---------------- fused QKV GEMM v2: 256x192 tile, BK=64, 4-phase pipeline ----
// A = xb [4096][1024], BT = WT [3072][1024]. Grid 16x16 = 256 blocks (1/CU).
// 8 waves (2M x 4N): wave (wr,wcn) owns rows wr*128+[0,128), cols wcn*48+[0,48).
// LDS: A dbuf 2x16K shorts, B dbuf 2x12K shorts (112 KB); granule-XOR swizzle
// g' = g ^ (row&7) on 16B granules (bank-balanced for stride-128B b128 reads).
// Per K-tile: 4 phases {ds_reads; stage-next glds; barrier; lgkm(0); setprio
// MFMA x12}; 7 glds/thread/tile spread 2/2/2/1; single vmcnt(2) at phase 0
// (waits exactly the previous tile's 7 loads, leaves 2 in flight).
__global__ __launch_bounds__(512, 2) void qkv_gemm_kernel(
    const short* __restrict__ A, const short* __restrict__ BT,
    const float* __restrict__ bq, const float* __restrict__ bk, const float* __restrict__ bv,
    short* __restrict__ Qb, short* __restrict__ Kb, short* __restrict__ VTb)
{
    __shared__ __align__(16) short sm[57344];   // 114688 B; epilogue reuses as [256][200]
    const int tid = threadIdx.x;
    const int l = tid & 63, w = tid >> 6;
    const int lr = l & 15, lk = l >> 4;
    const int wr = w >> 2, wcn = w & 3;

    // XCD swizzle: 32 consecutive remapped ids per XCD (2 bn-panels x 16 bm)
    const int id2 = (blockIdx.x & 7) * 32 + (blockIdx.x >> 3);
    const int bm = id2 & 15, bn = id2 >> 4;
    const int row0 = bm * 256, col0 = bn * 192;

    // staging: thread covers chunks c = tid + j*512 (row = c>>3, LDS granule c&7)
    const int gsrc8 = ((tid & 7) ^ ((tid >> 3) & 7)) << 3;
    const short* a_src = A + (size_t)(row0 + (tid >> 3)) * 1024 + gsrc8;
    const short* b_src = BT + (size_t)(col0 + (tid >> 3)) * 1024 + gsrc8;

    // fragment read offsets (elements)
    const int aBase = (wr * 128 + lr) * 64;
    const int bBase = (wcn * 48 + lr) * 64;
    const int asw0 = ((lk)     ^ (lr & 7)) << 3;   // kk=0 granule
    const int asw1 = ((lk + 4) ^ (lr & 7)) << 3;   // kk=1 granule

    f32x4 acc[8][3];
#pragma unroll
    for (int m = 0; m < 8; ++m)
#pragma unroll
        for (int n = 0; n < 3; ++n) acc[m][n] = (f32x4){0.f, 0.f, 0.f, 0.f};

    // prologue: stage K-tile 0 (7 loads, order = A0..A3,B0..B2)
    gld_lds16(a_src,          sm + tid * 8);
    gld_lds16(a_src + 65536,  sm + tid * 8 + 4096);
    gld_lds16(a_src + 131072, sm + tid * 8 + 8192);
    gld_lds16(a_src + 196608, sm + tid * 8 + 12288);
    gld_lds16(b_src,          sm + 32768 + tid * 8);
    gld_lds16(b_src + 65536,  sm + 32768 + tid * 8 + 4096);
    gld_lds16(b_src + 131072, sm + 32768 + tid * 8 + 8192);

#define PHASE(P, GLDS)                                                          \
    do {                                                                        \
        bf16x8 af[2][2];                                                        \
        af[0][0] = *(const bf16x8*)(Al + aBase + (2*(P))*1024 + asw0);          \
        af[0][1] = *(const bf16x8*)(Al + aBase + (2*(P))*1024 + asw1);          \
        af[1][0] = *(const bf16x8*)(Al + aBase + (2*(P)+1)*1024 + asw0);        \
        af[1][1] = *(const bf16x8*)(Al + aBase + (2*(P)+1)*1024 + asw1);        \
        GLDS;                                                                   \
        __builtin_amdgcn_s_barrier();                                           \
        asm volatile("s_waitcnt lgkmcnt(0)" ::: "memory");                      \
        __builtin_amdgcn_sched_barrier(0);                                      \
        __builtin_amdgcn_s_setprio(1);                                          \
        _Pragma("unroll")                                                       \
        for (int mm = 0; mm < 2; ++mm)                                          \
            _Pragma("unroll")                                                   \
            for (int n = 0; n < 3; ++n) {                                       \
                acc[2*(P)+mm][n] = MFMA32(af[mm][0], bfv[n][0], acc[2*(P)+mm][n]); \
                acc[2*(P)+mm][n] = MFMA32(af[mm][1], bfv[n][1], acc[2*(P)+mm][n]); \
            }                                                                   \
        __builtin_amdgcn_s_setprio(0);                                          \
        __builtin_amdgcn_s_barrier();                                           \
    } while (0)

#pragma unroll 2
    for (int kt = 0; kt < 16; ++kt) {
        const int cur = kt & 1, nxt = cur ^ 1;
        const short* Al = sm + cur * 16384;
        const short* Bl = sm + 32768 + cur * 12288;
        short* And = sm + nxt * 16384;
        short* Bnd = sm + 32768 + nxt * 12288;
        const int k1 = (kt + 1) * 64;
        const bool more = (kt < 15);

        bf16x8 bfv[3][2];

        // ===== phase 0: wait prev tile, read m=0,1 + all B =====
        if (more) {
            gld_lds16(a_src + k1,         And + tid * 8);
            gld_lds16(a_src + k1 + 65536, And + tid * 8 + 4096);
            asm volatile("s_waitcnt vmcnt(2)" ::: "memory");
        } else {
            asm volatile("s_waitcnt vmcnt(0)" ::: "memory");
        }
        __builtin_amdgcn_s_barrier();
        __builtin_amdgcn_sched_barrier(0);
        {
            bf16x8 af[2][2];
            af[0][0] = *(const bf16x8*)(Al + aBase + asw0);
            af[0][1] = *(const bf16x8*)(Al + aBase + asw1);
            af[1][0] = *(const bf16x8*)(Al + aBase + 1024 + asw0);
            af[1][1] = *(const bf16x8*)(Al + aBase + 1024 + asw1);
#pragma unroll
            for (int n = 0; n < 3; ++n) {
                bfv[n][0] = *(const bf16x8*)(Bl + bBase + n * 1024 + asw0);
                bfv[n][1] = *(const bf16x8*)(Bl + bBase + n * 1024 + asw1);
            }
            asm volatile("s_waitcnt lgkmcnt(0)" ::: "memory");
            __builtin_amdgcn_sched_barrier(0);
            __builtin_amdgcn_s_setprio(1);
#pragma unroll
            for (int mm = 0; mm < 2; ++mm)
#pragma unroll
                for (int n = 0; n < 3; ++n) {
                    acc[mm][n] = MFMA32(af[mm][0], bfv[n][0], acc[mm][n]);
                    acc[mm][n] = MFMA32(af[mm][1], bfv[n][1], acc[mm][n]);
                }
            __builtin_amdgcn_s_setprio(0);
        }
        __builtin_amdgcn_s_barrier();

        // ===== phases 1-3 =====
        PHASE(1, if (more) { gld_lds16(a_src + k1 + 131072, And + tid * 8 + 8192);
                             gld_lds16(a_src + k1 + 196608, And + tid * 8 + 12288); });
        PHASE(2, if (more) { gld_lds16(b_src + k1,          Bnd + tid * 8);
                             gld_lds16(b_src + k1 + 65536,  Bnd + tid * 8 + 4096); });
        PHASE(3, if (more) { gld_lds16(b_src + k1 + 131072, Bnd + tid * 8 + 8192); });
    }
#undef PHASE

    // ---------------- epilogue ----------------
    short* Cl = sm;   // [256][200] bf16 (row stride 400 B, 16B-aligned)
#pragma unroll
    for (int n = 0; n < 3; ++n) {
        const int gb = col0 + wcn * 48 + n * 16;   // 16-col-aligned: mat uniform
        const int mat = gb >> 10;
        const int jj = (gb + lr) & 1023;
        if (mat < 2) {
            const float bias = ((mat == 0) ? bq : bk)[jj];
            const float sc = (mat == 0) ? SCALE_Q : 1.0f;
            const int cc = wcn * 48 + n * 16 + lr;
#pragma unroll
            for (int m = 0; m < 8; ++m) {
                const int rbase = wr * 128 + m * 16 + lk * 4;
#pragma unroll
                for (int r = 0; r < 4; ++r)
                    Cl[(rbase + r) * 200 + cc] = f2b((acc[m][n][r] + bias) * sc);
            }
        } else {
            // V^T with per-64-block column permutation: g=8kk+4b0+lk -> g'=8kk+2lk+b0
            const float bias = bv[jj];
            const int h = jj >> 6, d = jj & 63;
#pragma unroll
            for (int m = 0; m < 8; ++m) {
                const int grow0 = row0 + wr * 128 + m * 16 + lk * 4;
                const int bb = grow0 >> 11, ns0 = grow0 & 2047;
                const int g = (ns0 >> 2) & 15;
                const int gp = (g & 8) | ((g & 3) << 1) | ((g >> 2) & 1);
                const int nsp = (ns0 & ~63) | (gp << 2);
                short4v pv;
#pragma unroll
                for (int r = 0; r < 4; ++r) pv[r] = f2b(acc[m][n][r] + bias);
                *(short4v*)(VTb + ((size_t)(bb * NHEAD + h) * DEPTH + d) * SEQ_N + nsp) = pv;
            }
        }
    }
    __syncthreads();
    // coalesced Q/K writeout: thread = (row, half); 12 x 16B contiguous stores
    // (2 threads/row x 12 granules x 8 shorts = all 192 columns)
    {
        const int row = tid >> 1, half = tid & 1;
        const int grow = row0 + row;
        const int bb = grow >> 11, ns = grow & 2047;
#pragma unroll
        for (int i = 0; i < 12; ++i) {
            const int cc = half * 96 + i * 8;
            const int gc = col0 + cc;
            const int mat = gc >> 10;
            if (mat < 2) {
                short* O = mat ? Kb : Qb;
                const int h = (gc & 1023) >> 6, d0 = gc & 63;
                *(bf16x8*)(O + ((size_t)(bb * NHEAD + h) * SEQ_N + ns) * DEPTH + d0) =
                    *(const bf16x8*)(Cl + row * 200 + cc);
            }
        }
    }
}

// ---------------- flash attention (R15: 4 waves, 2 blocks/CU, fixed-offset softmax) ----
// 4 waves x 32 q = 128 q rows per block; grid = 32 bh x 16 q-tiles = 512 blocks
// -> 2 blocks/CU (64 KB LDS each), de-phased barriers hide the vmcnt(0) drain.
// Super-tile = 128 keys (2 x 64 sub-tiles), double-buffered LDS, ONE
// vmcnt(0)+barrier per super-tile. Waves process sub-tiles in opposite order
// (sub = ss ^ (w&1)) to de-phase ds_read/MFMA/softmax bursts.
// S^T[key][q] = mfma32(A=K, B=Q) with accumulator INITIALIZED TO M_OFF=-12:
// P = exp2(S-12) directly (no running max / no rescale; exact ratios, bf16-safe).
// l: per-lane VALU partials reduced via shfl_xor(16/32) in the epilogue.

__device__ __forceinline__ float exppack32_lane(const f32x4 s[4], bf16x8 pb[2]) {
    float rs = 0.f;
#pragma unroll
    for (int kk = 0; kk < 2; ++kk) {
        union { unsigned u[4]; bf16x8 v; } pk;
#pragma unroll
        for (int hh = 0; hh < 2; ++hh) {
            const int c = 2 * kk + hh;
            const float p0 = FEXP2(s[c][0]);
            const float p1 = FEXP2(s[c][1]);
            const float p2 = FEXP2(s[c][2]);
            const float p3 = FEXP2(s[c][3]);
            rs += (p0 + p1) + (p2 + p3);
            pk.u[2 * hh]     = cvt_pk_bf16(p0, p1);
            pk.u[2 * hh + 1] = cvt_pk_bf16(p2, p3);
        }
        pb[kk] = pk.v;
    }
    return rs;   // per-lane partial; reduced across lk at the very end
}

#define NT 16   // 2048 / 128 super-tiles

__global__ __launch_bounds__(256, 2) void attn_kernel(
    const short* __restrict__ Qb, const short* __restrict__ Kb,
    const short* __restrict__ VTb, float* __restrict__ out)
{
    __shared__ short smem[2][16384];   // [buf][K0|K1|V0|V1] = 64 KB

    const int tid = threadIdx.x;
    const int l = tid & 63, w = tid >> 6;     // 4 waves
    const int lr = l & 15, lk = l >> 4;

    // XCD swizzle: 512 blocks -> 64/XCD = 4 bh x 16 q-tiles contiguous per XCD
    const int hb = blockIdx.x;
    const int slot = hb >> 3;                 // 0..63
    const int bh = (hb & 7) * 4 + (slot >> 4);
    const int qt = slot & 15;
    const int b = bh >> 4, h = bh & 15;

    const int qw = qt * 128 + w * 32;   // wave owns 32 q rows (2 groups of 16)

    const short* Qg = Qb + ((size_t)bh * SEQ_N + qw + lr) * DEPTH + lk * 8;
    const bf16x8 bq00 = *(const bf16x8*)(Qg);
    const bf16x8 bq01 = *(const bf16x8*)(Qg + 32);
    const bf16x8 bq10 = *(const bf16x8*)(Qg + 16 * DEPTH);
    const bf16x8 bq11 = *(const bf16x8*)(Qg + 16 * DEPTH + 32);

    const short* Kg = Kb + (size_t)bh * SEQ_N * DEPTH;    // [key][d]
    const short* Vg = VTb + (size_t)bh * DEPTH * SEQ_N;   // [d][key'] (permuted)

    // staging (256 thr): thread covers 16B chunk tid per 4KB half-region;
    // LDS[row][gl] = global[row][gl^(row&7)]; (row+32)&7 == row&7 so same granule.
    const int srow = tid >> 3;                // 0..31
    const int sg = (tid & 7) ^ (srow & 7);
    const short* Ksrc = Kg + (size_t)srow * DEPTH + sg * 8;   // + key*DEPTH per call
    const short* Vsrc = Vg + (size_t)srow * SEQ_N + sg * 8;   // + key per call

#define STAGE(BUF, T)                                                            \
    do {                                                                         \
        const int key0_ = (T) * 128;                                             \
        short* dst = &smem[BUF][w * 512];                                        \
        gld_lds16(Ksrc + (size_t)key0_ * DEPTH, dst);                            \
        gld_lds16(Ksrc + (size_t)(key0_ + 32) * DEPTH, dst + 2048);              \
        gld_lds16(Ksrc + (size_t)(key0_ + 64) * DEPTH, dst + 4096);              \
        gld_lds16(Ksrc + (size_t)(key0_ + 96) * DEPTH, dst + 6144);              \
        gld_lds16(Vsrc + key0_, dst + 8192);                                     \
        gld_lds16(Vsrc + key0_ + 32 * SEQ_N, dst + 10240);                       \
        gld_lds16(Vsrc + key0_ + 64, dst + 12288);                               \
        gld_lds16(Vsrc + key0_ + 64 + 32 * SEQ_N, dst + 14336);                  \
    } while (0)

    // hoisted per-lane fragment offsets (elements): row base + XOR granule
    const short* s0p = &smem[0][0];
    const int aoff0 = lr * 64 + (((lk    ) ^ (lr & 7)) << 3);   // kk=0
    const int aoff1 = lr * 64 + (((lk + 4) ^ (lr & 7)) << 3);   // kk=1

    f32x4 acc0[4], acc1[4];
#pragma unroll
    for (int n = 0; n < 4; ++n) {
        acc0[n] = (f32x4){0.f, 0.f, 0.f, 0.f};
        acc1[n] = (f32x4){0.f, 0.f, 0.f, 0.f};
    }
    float l0 = 0.f, l1 = 0.f;

    // prologue: stage super-tile 0
    STAGE(0, 0);
    asm volatile("s_waitcnt vmcnt(0)" ::: "memory");
    __builtin_amdgcn_s_barrier();
    __builtin_amdgcn_sched_barrier(0);

#pragma unroll 2
    for (int t = 0; t < NT; ++t) {
        const int cur = t & 1;
        const int tn = (t + 1 < NT) ? (t + 1) : (NT - 1);
        STAGE(cur ^ 1, tn);

        // two 64-key sub-tiles, wave-staggered order, no barrier between them
#pragma unroll
        for (int ss = 0; ss < 2; ++ss) {
            const int sub = ss ^ (w & 1);
            const short* Kl = s0p + cur * 16384 + sub * 4096;
            const short* Vl = Kl + 8192;

            bf16x8 kf[4][2], vf[4][2];
#pragma unroll
            for (int c = 0; c < 4; ++c) {
                kf[c][0] = *(const bf16x8*)(Kl + c * 1024 + aoff0);
                kf[c][1] = *(const bf16x8*)(Kl + c * 1024 + aoff1);
            }
#pragma unroll
            for (int n = 0; n < 4; ++n) {
                vf[n][0] = *(const bf16x8*)(Vl + n * 1024 + aoff0);
                vf[n][1] = *(const bf16x8*)(Vl + n * 1024 + aoff1);
            }

            // QK^T with C init = M_OFF (bakes the fixed softmax offset)
            f32x4 s0[4], s1[4];
            __builtin_amdgcn_s_setprio(1);
#pragma unroll
            for (int c = 0; c < 4; ++c) {
                f32x4 a = (f32x4){M_OFF, M_OFF, M_OFF, M_OFF};
                a = MFMA32(kf[c][0], bq00, a);
                a = MFMA32(kf[c][1], bq01, a);
                s0[c] = a;
                f32x4 bb2 = (f32x4){M_OFF, M_OFF, M_OFF, M_OFF};
                bb2 = MFMA32(kf[c][0], bq10, bb2);
                bb2 = MFMA32(kf[c][1], bq11, bb2);
                s1[c] = bb2;
            }
            __builtin_amdgcn_s_setprio(0);

            // fixed-offset softmax: P = exp2(s) directly, pack to bf16
            bf16x8 pb0[2], pb1[2];
            l0 += exppack32_lane(s0, pb0);
            l1 += exppack32_lane(s1, pb1);

            // PV over permuted key order
            __builtin_amdgcn_s_setprio(1);
#pragma unroll
            for (int n = 0; n < 4; ++n) {
                acc0[n] = MFMA32(vf[n][0], pb0[0], acc0[n]);
                acc0[n] = MFMA32(vf[n][1], pb0[1], acc0[n]);
                acc1[n] = MFMA32(vf[n][0], pb1[0], acc1[n]);
                acc1[n] = MFMA32(vf[n][1], pb1[1], acc1[n]);
            }
            __builtin_amdgcn_s_setprio(0);
        }

        asm volatile("s_waitcnt vmcnt(0)" ::: "memory");
        __builtin_amdgcn_s_barrier();
        __builtin_amdgcn_sched_barrier(0);
    }
#undef STAGE

    // final cross-lane l reduction (row-mates lk=0..3 hold disjoint key subsets)
    l0 += __shfl_xor(l0, 16); l0 += __shfl_xor(l0, 32);
    l1 += __shfl_xor(l1, 16); l1 += __shfl_xor(l1, 32);

    const float inv0 = 1.0f / l0, inv1 = 1.0f / l1;
    float* o0 = out + ((size_t)b * SEQ_N + qw + lr) * 1024 + h * 64 + lk * 4;
    float* o1 = o0 + (size_t)16 * 1024;
#pragma unroll
    for (int n = 0; n < 4; ++n) {
        const f32x4 v0 = acc0[n] * inv0;
        const f32x4 v1 = acc1[n] * inv1;
        *(f32x4*)(o0 + n * 16) = v0;
        *(f32x4*)(o1 + n * 16) = v1;
    }
}

extern "C" void kernel_launch(void* const* d_in, const int* in_sizes, int n_in,
                              void* d_out, int out_size, void* d_ws, size_t ws_size,
                              hipStream_t stream) {
    const float* x  = (const float*)d_in[0];
    const float* Wq = (const float*)d_in[1];
    const float* bq = (const float*)d_in[2];
    const float* Wk = (const float*)d_in[3];
    const float* bk = (const float*)d_in[4];
    const float* Wv = (const float*)d_in[5];
    const float* bv = (const float*)d_in[6];
    float* out = (float*)d_out;

    char* ws = (char*)d_ws;
    short* xb  = (short*)(ws);                      // 8 MB
    short* WT  = (short*)(ws + (8  << 20));         // 6 MB
    short* Qb  = (short*)(ws + (14 << 20));         // 8 MB
    short* Kb  = (short*)(ws + (22 << 20));         // 8 MB
    short* VTb = (short*)(ws + (30 << 20));         // 8 MB

    cvt_all_kernel<<<2816, 256, 0, stream>>>(x, xb, Wq, Wk, Wv, WT);
    qkv_gemm_kernel<<<256, 512, 0, stream>>>(xb, WT, bq, bk, bv, Qb, Kb, VTb);
    attn_kernel<<<512, 256, 0, stream>>>(Qb, Kb, VTb, out);
}